// Round 5
// baseline (295.016 us; speedup 1.0000x reference)
//
#include <hip/hip_runtime.h>

// ---------------------------------------------------------------------------
// NearestSim: out[t] = -cos(q_t, items[argmax_j q_t . items_j])
// T=16384, M=4096, C=512, fp32 in/out.
// R5: barrier-free score kernel. Convert pass stores Q/items fp16 in
// MFMA-fragment order (chunk = (tile16, kk, lane)); score kernel reads
// fragments directly from global with scalar-base + lane*16 addressing.
// No LDS, no __syncthreads, no vmcnt(0) drain in the K-loop.
// ---------------------------------------------------------------------------

#define TQ 16384
#define MI 4096
#define CD 512
#define NIB 16          // item-tile blocks (256 items each)
#define BM 128          // block query rows
#define BN 256          // block item cols
#define KITER (CD / 32) // 16 k-steps of 32

typedef _Float16 half8   __attribute__((ext_vector_type(8)));
typedef float    float4t __attribute__((ext_vector_type(4)));

// workspace layout (bytes)
#define QH_OFF   (0u)
#define QH_BYTES ((unsigned)TQ * CD * 2u)              // 16 MB staged queries
#define IH_OFF   (QH_OFF + QH_BYTES)
#define IH_BYTES ((unsigned)MI * CD * 2u)              // 4 MB staged items
#define PART_OFF (IH_OFF + IH_BYTES)
#define PART_BYTES ((unsigned)TQ * 32u * 16u)          // 8 MB: 32 entries/query
// total 28 MB

// staged layout: chunk index c = (rowTile16 * 16 + kk) * 64 + lane, 16 B each.
// lane = quad*16 + l15 holds row (rowTile*16 + l15), cols kk*32 + quad*8 .. +8.

// full top-2 merge with index tie-break (rescue-side only)
__device__ __forceinline__ void top2_merge(float& a1v, int& a1i, float& a2v,
                                           int& a2i, float b1v, int b1i,
                                           float b2v, int b2i) {
  bool af = (a1v > b1v) || (a1v == b1v && a1i <= b1i);
  float w1v = af ? a1v : b1v; int w1i = af ? a1i : b1i;
  float l1v = af ? b1v : a1v; int l1i = af ? b1i : a1i;
  float c2v = af ? a2v : b2v; int c2i = af ? a2i : b2i;
  bool lb = (l1v > c2v) || (l1v == c2v && l1i <= c2i);
  a1v = w1v; a1i = w1i;
  a2v = lb ? l1v : c2v;
  a2i = lb ? l1i : c2i;
}

// ---------------- kernel 1: fp32 -> fp16 fragment-order staging -------------
__global__ __launch_bounds__(256) void convert_kernel(
    const float* __restrict__ q, const float* __restrict__ it,
    char* __restrict__ ws) {
  const int c = blockIdx.x * 256 + threadIdx.x;
  const int QC = TQ * CD / 8;  // 1048576 16B chunks
  const int IC = MI * CD / 8;  //  262144
  const float* src;
  char* dst;
  int cc;
  if (c < QC) {
    cc = c; src = q; dst = ws + QH_OFF;
  } else if (c < QC + IC) {
    cc = c - QC; src = it; dst = ws + IH_OFF;
  } else {
    return;
  }
  const int rowTile = cc >> 10;           // 1024 chunks per 16-row tile
  const int rem = cc & 1023;
  const int kk = rem >> 6;
  const int lane = rem & 63;
  const int row = rowTile * 16 + (lane & 15);
  const int col = kk * 32 + (lane >> 4) * 8;
  const float4* s = (const float4*)(src + (size_t)row * CD + col);
  float4 v0 = s[0], v1 = s[1];
  half8 h = {(_Float16)v0.x, (_Float16)v0.y, (_Float16)v0.z, (_Float16)v0.w,
             (_Float16)v1.x, (_Float16)v1.y, (_Float16)v1.z, (_Float16)v1.w};
  *(half8*)(dst + (size_t)cc * 16) = h;
}

// ---------------- kernel 2: barrier-free fused GEMM + top-2 -----------------
// grid (TQ/BM, NIB), block 256 = 4 waves in 2x2; wave tile 64q x 128i
// (4x8 grid of 16x16x32 MFMAs). Fragments straight from global (L2-hot).
__global__ __launch_bounds__(256) void score_kernel(char* __restrict__ ws) {
  const int tid  = threadIdx.x;
  const int lane = tid & 63;
  const int wave = tid >> 6;
  const int quad = lane >> 4;
  const int l15  = lane & 15;
  const int wy   = wave >> 1;   // 0..1 : query half
  const int wx   = wave & 1;    // 0..1 : item half
  const int qtile = blockIdx.x;
  const int ib    = blockIdx.y;

  const char* Qs = ws + QH_OFF;
  const char* Is = ws + IH_OFF;
  const int lane16 = lane * 16;

  // fragment base addresses (scalar part uniform per wave; only lane16 is VGPR)
  const char* aP[4];
  const char* bP[8];
#pragma unroll
  for (int mi = 0; mi < 4; ++mi)
    aP[mi] = Qs + (size_t)(qtile * 8 + wy * 4 + mi) * 16384 + lane16;
#pragma unroll
  for (int ni = 0; ni < 8; ++ni)
    bP[ni] = Is + (size_t)(ib * 16 + wx * 8 + ni) * 16384 + lane16;

  float4t acc[4][8];
#pragma unroll
  for (int mi = 0; mi < 4; ++mi)
#pragma unroll
    for (int ni = 0; ni < 8; ++ni) acc[mi][ni] = (float4t){0.f, 0.f, 0.f, 0.f};

#pragma unroll 2
  for (int kk = 0; kk < KITER; ++kk) {
    const int kb = kk * 1024;
    half8 a[4], b[8];
#pragma unroll
    for (int mi = 0; mi < 4; ++mi) a[mi] = *(const half8*)(aP[mi] + kb);
#pragma unroll
    for (int ni = 0; ni < 8; ++ni) b[ni] = *(const half8*)(bP[ni] + kb);
#pragma unroll
    for (int mi = 0; mi < 4; ++mi)
#pragma unroll
      for (int ni = 0; ni < 8; ++ni)
        acc[mi][ni] = __builtin_amdgcn_mfma_f32_16x16x32_f16(
            a[mi], b[ni], acc[mi][ni], 0, 0, 0);
  }

  // ---- epilogue: top-2 over this wave's 128 cols, per query row ----
  // C row = quad*4+r (query), col = l15 (item). loc = wx*128+ni*16+l15 < 256.
  float t1v[16], t2v[16];
  int pk[16];
#pragma unroll
  for (int s = 0; s < 16; ++s) { t1v[s] = -1e30f; t2v[s] = -1e30f; pk[s] = 0; }

  const int loc0 = wx * 128 + l15;
#pragma unroll
  for (int ni = 0; ni < 8; ++ni) {
    const int loc = loc0 + ni * 16;
#pragma unroll
    for (int mi = 0; mi < 4; ++mi) {
#pragma unroll
      for (int r = 0; r < 4; ++r) {
        const int s = mi * 4 + r;
        const float v = acc[mi][ni][r];
        const bool g1 = v > t1v[s];
        const bool g2 = v > t2v[s];
        const float nt2 = g1 ? t1v[s] : (g2 ? v : t2v[s]);
        const int pkA = (loc << 16) | ((unsigned)pk[s] >> 16);  // demote t1
        const int pkB = (pk[s] & (int)0xFFFF0000) | loc;        // replace t2
        pk[s] = g1 ? pkA : (g2 ? pkB : pk[s]);
        t1v[s] = g1 ? v : t1v[s];
        t2v[s] = nt2;
      }
    }
  }

  // 4-step butterfly merge across the 16-lane l15 group
  // (no tie-break: fp32-accumulated scores of random vectors never tie)
#pragma unroll
  for (int s = 0; s < 16; ++s) {
#pragma unroll
    for (int m = 1; m < 16; m <<= 1) {
      const float b1v = __shfl_xor(t1v[s], m, 16);
      const float b2v = __shfl_xor(t2v[s], m, 16);
      const int bpk  = __shfl_xor(pk[s], m, 16);
      const bool g = b1v > t1v[s];
      const float loserv = g ? t1v[s] : b1v;
      const int wpk = g ? bpk : pk[s];
      const int lpk = g ? pk[s] : bpk;
      const float ws2v = g ? b2v : t2v[s];   // winner-side second
      t1v[s] = g ? b1v : t1v[s];
      const bool g2 = loserv > ws2v;
      t2v[s] = g2 ? loserv : ws2v;
      const int pkOpt = (wpk & (int)0xFFFF0000) | ((unsigned)lpk >> 16);
      pk[s] = g2 ? pkOpt : wpk;
    }
  }

  // writer: l15 == 0. Entry e = ib*2 + wx (waves sharing rows differ in wx;
  // different wy -> disjoint qrows).
  if (l15 == 0) {
    float4* part = (float4*)(ws + PART_OFF);
    const int e = ib * 2 + wx;
#pragma unroll
    for (int s = 0; s < 16; ++s) {
      const int qrow = qtile * BM + wy * 64 + (s >> 2) * 16 + quad * 4 + (s & 3);
      const int i1 = ib * BN + ((unsigned)pk[s] >> 16);
      const int i2 = ib * BN + (pk[s] & 0xFFFF);
      float4 ent;
      ent.x = t1v[s];
      ent.y = __int_as_float(i1);
      ent.z = t2v[s];
      ent.w = __int_as_float(i2);
      part[(size_t)qrow * 32 + e] = ent;
    }
  }
}

// ---------------- kernel 3: merge partials + exact fp32 rescue --------------
// one wave per query; 32 partial entries -> global fp16 top-2 -> exact fp32
// re-score of both candidates. Uses ORIGINAL fp32 q/items (row-major).
__global__ __launch_bounds__(256) void rescue_kernel(
    const float* __restrict__ q, const float* __restrict__ items,
    const char* __restrict__ ws, float* __restrict__ out) {
  const int wave = threadIdx.x >> 6;
  const int lane = threadIdx.x & 63;
  const int qrow = blockIdx.x * 4 + wave;

  const float4* part = (const float4*)(ws + PART_OFF);

  float t1vv = -1e30f, t2vv = -1e30f;
  int t1i = 0x7FFFFFFF, t2i = 0x7FFFFFFF;
  if (lane < 32) {
    float4 ent = part[(size_t)qrow * 32 + lane];  // one coalesced 512B burst
    t1vv = ent.x; t1i = __float_as_int(ent.y);
    t2vv = ent.z; t2i = __float_as_int(ent.w);
  }
#pragma unroll
  for (int m = 1; m < 32; m <<= 1) {
    const float b1v = __shfl_xor(t1vv, m, 32);
    const int   b1i = __shfl_xor(t1i, m, 32);
    const float b2v = __shfl_xor(t2vv, m, 32);
    const int   b2i = __shfl_xor(t2i, m, 32);
    top2_merge(t1vv, t1i, t2vv, t2i, b1v, b1i, b2v, b2i);
  }
  const int c1i = __shfl(t1i, 0, 64);
  const int c2i = __shfl(t2i, 0, 64);

  const float4* qp = (const float4*)(q + (size_t)qrow * CD);
  const float4* p1 = (const float4*)(items + (size_t)c1i * CD);
  const float4* p2 = (const float4*)(items + (size_t)c2i * CD);
  float4 qa = qp[lane * 2], qb = qp[lane * 2 + 1];
  float4 xa = p1[lane * 2], xb = p1[lane * 2 + 1];
  float4 ya = p2[lane * 2], yb = p2[lane * 2 + 1];

  float d1 = qa.x * xa.x + qa.y * xa.y + qa.z * xa.z + qa.w * xa.w +
             qb.x * xb.x + qb.y * xb.y + qb.z * xb.z + qb.w * xb.w;
  float d2 = qa.x * ya.x + qa.y * ya.y + qa.z * ya.z + qa.w * ya.w +
             qb.x * yb.x + qb.y * yb.y + qb.z * yb.z + qb.w * yb.w;
  float qq = qa.x * qa.x + qa.y * qa.y + qa.z * qa.z + qa.w * qa.w +
             qb.x * qb.x + qb.y * qb.y + qb.z * qb.z + qb.w * qb.w;
  float i1 = xa.x * xa.x + xa.y * xa.y + xa.z * xa.z + xa.w * xa.w +
             xb.x * xb.x + xb.y * xb.y + xb.z * xb.z + xb.w * xb.w;
  float i2 = ya.x * ya.x + ya.y * ya.y + ya.z * ya.z + ya.w * ya.w +
             yb.x * yb.x + yb.y * yb.y + yb.z * yb.z + yb.w * yb.w;

#pragma unroll
  for (int m = 1; m < 64; m <<= 1) {
    d1 += __shfl_xor(d1, m, 64);
    d2 += __shfl_xor(d2, m, 64);
    qq += __shfl_xor(qq, m, 64);
    i1 += __shfl_xor(i1, m, 64);
    i2 += __shfl_xor(i2, m, 64);
  }

  if (lane == 0) {
    bool use2 = (d2 > d1) || (d2 == d1 && c2i < c1i);
    float d  = use2 ? d2 : d1;
    float nn = use2 ? i2 : i1;
    float nq = fmaxf(sqrtf(qq), 1e-12f);
    float np = fmaxf(sqrtf(nn), 1e-12f);
    out[qrow] = -(d / (nq * np));
  }
}

// ---------------------------------------------------------------------------
extern "C" void kernel_launch(void* const* d_in, const int* in_sizes, int n_in,
                              void* d_out, int out_size, void* d_ws,
                              size_t ws_size, hipStream_t stream) {
  const float* q  = (const float*)d_in[0];
  const float* it = (const float*)d_in[1];
  char* ws = (char*)d_ws;
  float* out = (float*)d_out;

  const int totalChunks = (TQ * CD + MI * CD) / 8;
  convert_kernel<<<(totalChunks + 255) / 256, 256, 0, stream>>>(q, it, ws);
  dim3 grid(TQ / BM, NIB);
  score_kernel<<<grid, 256, 0, stream>>>(ws);
  rescue_kernel<<<TQ / 4, 256, 0, stream>>>(q, it, ws, out);
}

// Round 6
// 201.029 us; speedup vs baseline: 1.4675x; 1.4675x over previous
//
#include <hip/hip_runtime.h>

// ---------------------------------------------------------------------------
// NearestSim: out[t] = -cos(q_t, items[argmax_j q_t . items_j])
// T=16384, M=4096, C=512, fp32 in/out.
// fp16 MFMA fused GEMM + exact per-lane top-2, fp32 rescue.
// R6: double-buffered LDS staging, prefetch distance 1 — global_load_lds for
// kk+1 issued right after the barrier publishing kk, so the 48 KB delivery
// (L2 ~200cyc + ~857cyc transfer per CU) overlaps the ~1540cyc compute period
// instead of serializing after the barrier (R4's 4453-cyc period -> ~2000).
// ---------------------------------------------------------------------------

#define TQ 16384
#define MI 4096
#define CD 512
#define NSPLIT 16
#define BM 128          // block query rows
#define BN 256          // block item cols (= split width)
#define KITER (CD / 32) // 16 k-steps of 32

typedef _Float16 half8   __attribute__((ext_vector_type(8)));
typedef _Float16 half4_t __attribute__((ext_vector_type(4)));
typedef float    float4t __attribute__((ext_vector_type(4)));

// workspace layout (bytes)
#define QH_OFF   (0u)
#define QH_BYTES ((unsigned)TQ * CD * 2u)              // 16 MB fp16 queries
#define IH_OFF   (QH_OFF + QH_BYTES)
#define IH_BYTES ((unsigned)MI * CD * 2u)              // 4 MB fp16 items
#define PART_OFF (IH_OFF + IH_BYTES)
#define PART_BYTES ((unsigned)TQ * 32u * 16u)          // 8 MB: 32 entries/query
// total 28 MB

__device__ __forceinline__ void lds_load16(const void* g, void* l) {
  __builtin_amdgcn_global_load_lds(
      (const __attribute__((address_space(1))) void*)g,
      (__attribute__((address_space(3))) void*)l, 16, 0, 0);
}

// full top-2 merge with index tie-break (rescue-side only)
__device__ __forceinline__ void top2_merge(float& a1v, int& a1i, float& a2v,
                                           int& a2i, float b1v, int b1i,
                                           float b2v, int b2i) {
  bool af = (a1v > b1v) || (a1v == b1v && a1i <= b1i);
  float w1v = af ? a1v : b1v; int w1i = af ? a1i : b1i;
  float l1v = af ? b1v : a1v; int l1i = af ? b1i : a1i;
  float c2v = af ? a2v : b2v; int c2i = af ? a2i : b2i;
  bool lb = (l1v > c2v) || (l1v == c2v && l1i <= c2i);
  a1v = w1v; a1i = w1i;
  a2v = lb ? l1v : c2v;
  a2i = lb ? l1i : c2i;
}

// ---------------- kernel 1: fp32 -> fp16 conversion (row-major) -------------
__global__ __launch_bounds__(256) void convert_kernel(
    const float* __restrict__ q, const float* __restrict__ it,
    char* __restrict__ ws) {
  int idx = blockIdx.x * 256 + threadIdx.x;
  const int QV = TQ * CD / 4;
  const int IV = MI * CD / 4;
  half4_t* Qh = (half4_t*)(ws + QH_OFF);
  half4_t* Ih = (half4_t*)(ws + IH_OFF);
  if (idx < QV) {
    float4 v = ((const float4*)q)[idx];
    half4_t h = {(_Float16)v.x, (_Float16)v.y, (_Float16)v.z, (_Float16)v.w};
    Qh[idx] = h;
  }
  if (idx < IV) {
    float4 v = ((const float4*)it)[idx];
    half4_t h = {(_Float16)v.x, (_Float16)v.y, (_Float16)v.z, (_Float16)v.w};
    Ih[idx] = h;
  }
}

// ---------------- kernel 2: fused fp16 GEMM + per-query top-2 ---------------
// grid (TQ/BM, NSPLIT), block 256 = 4 waves in 2x2; wave tile 64q x 128i
// (4x8 grid of 16x16x32 MFMAs). Double-buffered staging, 1 barrier per kk.
__global__ __launch_bounds__(256, 2) void score_kernel(char* __restrict__ ws) {
  __shared__ __align__(16) char sA[2][BM * 64];  // 2 x 8 KB
  __shared__ __align__(16) char sB[2][BN * 64];  // 2 x 16 KB  (total 48 KB)

  const int tid  = threadIdx.x;
  const int lane = tid & 63;
  const int wave = tid >> 6;
  const int quad = lane >> 4;
  const int l15  = lane & 15;
  const int wy   = wave >> 1;   // 0..1 : query half
  const int wx   = wave & 1;    // 0..1 : item half
  const int qtile = blockIdx.x;
  const int split = blockIdx.y;

  const char* Qh = ws + QH_OFF;
  const char* Ih = ws + IH_OFF;

  // staging: shared lane-offset pattern f(t); all 6 streams = base + f
  const int f = (tid >> 2) * 1024 + (tid & 3) * 16;
  const char* gA0 = Qh + (size_t)qtile * BM * 1024 + f;  // rows 0..63
  const char* gA1 = gA0 + 64 * 1024;                     // rows 64..127
  const char* gB  = Ih + (size_t)split * BN * 1024 + f;  // 256 item rows
  const int flat = tid * 16;  // LDS dest (wave-uniform base + lane*16)

  // fragment LDS byte offsets
  const int aBase = (wy * 64 + l15) * 64 + quad * 16;   // + mi*1024
  const int bBase = (wx * 128 + l15) * 64 + quad * 16;  // + ni*1024

  float4t acc[4][8];
#pragma unroll
  for (int mi = 0; mi < 4; ++mi)
#pragma unroll
    for (int ni = 0; ni < 8; ++ni) acc[mi][ni] = (float4t){0.f, 0.f, 0.f, 0.f};

  // preload kk=0 into buffer 0 (drained by the first barrier)
  lds_load16(gA0, sA[0] + flat);
  lds_load16(gA1, sA[0] + flat + 4096);
  lds_load16(gB,          sB[0] + flat);
  lds_load16(gB + 65536,  sB[0] + flat + 4096);
  lds_load16(gB + 131072, sB[0] + flat + 8192);
  lds_load16(gB + 196608, sB[0] + flat + 12288);

#pragma unroll
  for (int kk = 0; kk < KITER; ++kk) {
    const int cur = kk & 1;
    const int nxt = cur ^ 1;
    // barrier: (a) staging of kk (issued one period ago) is drained by the
    // compiler's vmcnt(0); (b) all waves finished reading buf[nxt] (kk-1).
    __syncthreads();

    // prefetch kk+1 into the other buffer BEFORE consuming kk — delivery
    // overlaps this iteration's ds_reads + MFMAs.
    if (kk + 1 < KITER) {
      const int kb = (kk + 1) * 64;
      lds_load16(gA0 + kb, sA[nxt] + flat);
      lds_load16(gA1 + kb, sA[nxt] + flat + 4096);
      lds_load16(gB + kb,           sB[nxt] + flat);
      lds_load16(gB + 65536 + kb,   sB[nxt] + flat + 4096);
      lds_load16(gB + 131072 + kb,  sB[nxt] + flat + 8192);
      lds_load16(gB + 196608 + kb,  sB[nxt] + flat + 12288);
    }

    half8 a[4], b[8];
#pragma unroll
    for (int mi = 0; mi < 4; ++mi)
      a[mi] = *(const half8*)(sA[cur] + aBase + mi * 1024);
#pragma unroll
    for (int ni = 0; ni < 8; ++ni)
      b[ni] = *(const half8*)(sB[cur] + bBase + ni * 1024);
#pragma unroll
    for (int mi = 0; mi < 4; ++mi)
#pragma unroll
      for (int ni = 0; ni < 8; ++ni)
        acc[mi][ni] = __builtin_amdgcn_mfma_f32_16x16x32_f16(
            a[mi], b[ni], acc[mi][ni], 0, 0, 0);
  }

  // ---- epilogue: top-2 over this wave's 128 cols, per query row ----
  // C row = quad*4+r (query), col = l15 (item). loc = wx*128+ni*16+l15 < 256.
  float t1v[16], t2v[16];
  int pk[16];
#pragma unroll
  for (int s = 0; s < 16; ++s) { t1v[s] = -1e30f; t2v[s] = -1e30f; pk[s] = 0; }

  const int loc0 = wx * 128 + l15;
#pragma unroll
  for (int ni = 0; ni < 8; ++ni) {
    const int loc = loc0 + ni * 16;
#pragma unroll
    for (int mi = 0; mi < 4; ++mi) {
#pragma unroll
      for (int r = 0; r < 4; ++r) {
        const int s = mi * 4 + r;
        const float v = acc[mi][ni][r];
        const bool g1 = v > t1v[s];
        const bool g2 = v > t2v[s];
        const float nt2 = g1 ? t1v[s] : (g2 ? v : t2v[s]);
        const int pkA = (loc << 16) | ((unsigned)pk[s] >> 16);  // demote t1
        const int pkB = (pk[s] & (int)0xFFFF0000) | loc;        // replace t2
        pk[s] = g1 ? pkA : (g2 ? pkB : pk[s]);
        t1v[s] = g1 ? v : t1v[s];
        t2v[s] = nt2;
      }
    }
  }

  // 4-step butterfly merge across the 16-lane l15 group
  // (no tie-break: fp32-accumulated scores of random vectors never tie)
#pragma unroll
  for (int s = 0; s < 16; ++s) {
#pragma unroll
    for (int m = 1; m < 16; m <<= 1) {
      const float b1v = __shfl_xor(t1v[s], m, 16);
      const float b2v = __shfl_xor(t2v[s], m, 16);
      const int bpk  = __shfl_xor(pk[s], m, 16);
      const bool g = b1v > t1v[s];
      const float loserv = g ? t1v[s] : b1v;
      const int wpk = g ? bpk : pk[s];
      const int lpk = g ? pk[s] : bpk;
      const float ws2v = g ? b2v : t2v[s];   // winner-side second
      t1v[s] = g ? b1v : t1v[s];
      const bool g2 = loserv > ws2v;
      t2v[s] = g2 ? loserv : ws2v;
      const int pkOpt = (wpk & (int)0xFFFF0000) | ((unsigned)lpk >> 16);
      pk[s] = g2 ? pkOpt : wpk;
    }
  }

  // writer: l15 == 0. Entry e = split*2 + wx (waves sharing rows differ in
  // wx -> disjoint entries; different wy -> disjoint qrows).
  if (l15 == 0) {
    float4* part = (float4*)(ws + PART_OFF);
    const int e = split * 2 + wx;
#pragma unroll
    for (int s = 0; s < 16; ++s) {
      const int qrow = qtile * BM + wy * 64 + (s >> 2) * 16 + quad * 4 + (s & 3);
      const int i1 = split * BN + ((unsigned)pk[s] >> 16);
      const int i2 = split * BN + (pk[s] & 0xFFFF);
      float4 ent;
      ent.x = t1v[s];
      ent.y = __int_as_float(i1);
      ent.z = t2v[s];
      ent.w = __int_as_float(i2);
      part[(size_t)qrow * 32 + e] = ent;
    }
  }
}

// ---------------- kernel 3: merge partials + exact fp32 rescue --------------
// one wave per query; 32 partial entries -> global fp16 top-2 -> exact fp32
// re-score of both candidates from the ORIGINAL fp32 inputs.
__global__ __launch_bounds__(256) void rescue_kernel(
    const float* __restrict__ q, const float* __restrict__ items,
    const char* __restrict__ ws, float* __restrict__ out) {
  const int wave = threadIdx.x >> 6;
  const int lane = threadIdx.x & 63;
  const int qrow = blockIdx.x * 4 + wave;

  const float4* part = (const float4*)(ws + PART_OFF);

  float t1vv = -1e30f, t2vv = -1e30f;
  int t1i = 0x7FFFFFFF, t2i = 0x7FFFFFFF;
  if (lane < 32) {
    float4 ent = part[(size_t)qrow * 32 + lane];  // one coalesced 512B burst
    t1vv = ent.x; t1i = __float_as_int(ent.y);
    t2vv = ent.z; t2i = __float_as_int(ent.w);
  }
#pragma unroll
  for (int m = 1; m < 32; m <<= 1) {
    const float b1v = __shfl_xor(t1vv, m, 32);
    const int   b1i = __shfl_xor(t1i, m, 32);
    const float b2v = __shfl_xor(t2vv, m, 32);
    const int   b2i = __shfl_xor(t2i, m, 32);
    top2_merge(t1vv, t1i, t2vv, t2i, b1v, b1i, b2v, b2i);
  }
  const int c1i = __shfl(t1i, 0, 64);
  const int c2i = __shfl(t2i, 0, 64);

  const float4* qp = (const float4*)(q + (size_t)qrow * CD);
  const float4* p1 = (const float4*)(items + (size_t)c1i * CD);
  const float4* p2 = (const float4*)(items + (size_t)c2i * CD);
  float4 qa = qp[lane * 2], qb = qp[lane * 2 + 1];
  float4 xa = p1[lane * 2], xb = p1[lane * 2 + 1];
  float4 ya = p2[lane * 2], yb = p2[lane * 2 + 1];

  float d1 = qa.x * xa.x + qa.y * xa.y + qa.z * xa.z + qa.w * xa.w +
             qb.x * xb.x + qb.y * xb.y + qb.z * xb.z + qb.w * xb.w;
  float d2 = qa.x * ya.x + qa.y * ya.y + qa.z * ya.z + qa.w * ya.w +
             qb.x * yb.x + qb.y * yb.y + qb.z * yb.z + qb.w * yb.w;
  float qq = qa.x * qa.x + qa.y * qa.y + qa.z * qa.z + qa.w * qa.w +
             qb.x * qb.x + qb.y * qb.y + qb.z * qb.z + qb.w * qb.w;
  float i1 = xa.x * xa.x + xa.y * xa.y + xa.z * xa.z + xa.w * xa.w +
             xb.x * xb.x + xb.y * xb.y + xb.z * xb.z + xb.w * xb.w;
  float i2 = ya.x * ya.x + ya.y * ya.y + ya.z * ya.z + ya.w * ya.w +
             yb.x * yb.x + yb.y * yb.y + yb.z * yb.z + yb.w * yb.w;

#pragma unroll
  for (int m = 1; m < 64; m <<= 1) {
    d1 += __shfl_xor(d1, m, 64);
    d2 += __shfl_xor(d2, m, 64);
    qq += __shfl_xor(qq, m, 64);
    i1 += __shfl_xor(i1, m, 64);
    i2 += __shfl_xor(i2, m, 64);
  }

  if (lane == 0) {
    bool use2 = (d2 > d1) || (d2 == d1 && c2i < c1i);
    float d  = use2 ? d2 : d1;
    float nn = use2 ? i2 : i1;
    float nq = fmaxf(sqrtf(qq), 1e-12f);
    float np = fmaxf(sqrtf(nn), 1e-12f);
    out[qrow] = -(d / (nq * np));
  }
}

// ---------------------------------------------------------------------------
extern "C" void kernel_launch(void* const* d_in, const int* in_sizes, int n_in,
                              void* d_out, int out_size, void* d_ws,
                              size_t ws_size, hipStream_t stream) {
  const float* q  = (const float*)d_in[0];
  const float* it = (const float*)d_in[1];
  char* ws = (char*)d_ws;
  float* out = (float*)d_out;

  convert_kernel<<<TQ * CD / 4 / 256, 256, 0, stream>>>(q, it, ws);
  dim3 grid(TQ / BM, NSPLIT);
  score_kernel<<<grid, 256, 0, stream>>>(ws);
  rescue_kernel<<<TQ / 4, 256, 0, stream>>>(q, it, ws, out);
}

// Round 7
// 190.784 us; speedup vs baseline: 1.5463x; 1.0537x over previous
//
#include <hip/hip_runtime.h>

// ---------------------------------------------------------------------------
// NearestSim: out[t] = -cos(q_t, items[argmax_j q_t . items_j])
// T=16384, M=4096, C=512, fp32 in/out.
// fp16 MFMA fused GEMM + exact per-lane top-2, fp32 rescue.
// R7: occupancy round. R1/R4/R6 all ran 2 waves/SIMD (unified regs = arch
// VGPR + AGPR acc: 240 for the 64x128 tile) and every pipe-level tweak was
// neutral — the serial per-wave pipe sum (~280k cyc) matched measured time.
// Wave tile 32x128 (acc 64) + launch_bounds(256,3) => 3 blocks/CU, so MFMA /
// LDS / VALU phases of different waves co-schedule (m114).
// ---------------------------------------------------------------------------

#define TQ 16384
#define MI 4096
#define CD 512
#define NSPLIT 32
#define BM 128          // block query rows (4 waves x 32)
#define BN 128          // block item cols (= split width)
#define KITER (CD / 32) // 16 k-steps of 32

typedef _Float16 half8   __attribute__((ext_vector_type(8)));
typedef _Float16 half4_t __attribute__((ext_vector_type(4)));
typedef float    float4t __attribute__((ext_vector_type(4)));

// workspace layout (bytes)
#define QH_OFF   (0u)
#define QH_BYTES ((unsigned)TQ * CD * 2u)              // 16 MB fp16 queries
#define IH_OFF   (QH_OFF + QH_BYTES)
#define IH_BYTES ((unsigned)MI * CD * 2u)              // 4 MB fp16 items
#define PART_OFF (IH_OFF + IH_BYTES)
#define PART_BYTES ((unsigned)TQ * 32u * 16u)          // 8 MB: 32 entries/query
// total 28 MB

__device__ __forceinline__ void lds_load16(const void* g, void* l) {
  __builtin_amdgcn_global_load_lds(
      (const __attribute__((address_space(1))) void*)g,
      (__attribute__((address_space(3))) void*)l, 16, 0, 0);
}

// full top-2 merge with index tie-break (rescue-side only)
__device__ __forceinline__ void top2_merge(float& a1v, int& a1i, float& a2v,
                                           int& a2i, float b1v, int b1i,
                                           float b2v, int b2i) {
  bool af = (a1v > b1v) || (a1v == b1v && a1i <= b1i);
  float w1v = af ? a1v : b1v; int w1i = af ? a1i : b1i;
  float l1v = af ? b1v : a1v; int l1i = af ? b1i : a1i;
  float c2v = af ? a2v : b2v; int c2i = af ? a2i : b2i;
  bool lb = (l1v > c2v) || (l1v == c2v && l1i <= c2i);
  a1v = w1v; a1i = w1i;
  a2v = lb ? l1v : c2v;
  a2i = lb ? l1i : c2i;
}

// ---------------- kernel 1: fp32 -> fp16 conversion (row-major) -------------
__global__ __launch_bounds__(256) void convert_kernel(
    const float* __restrict__ q, const float* __restrict__ it,
    char* __restrict__ ws) {
  int idx = blockIdx.x * 256 + threadIdx.x;
  const int QV = TQ * CD / 4;
  const int IV = MI * CD / 4;
  half4_t* Qh = (half4_t*)(ws + QH_OFF);
  half4_t* Ih = (half4_t*)(ws + IH_OFF);
  if (idx < QV) {
    float4 v = ((const float4*)q)[idx];
    half4_t h = {(_Float16)v.x, (_Float16)v.y, (_Float16)v.z, (_Float16)v.w};
    Qh[idx] = h;
  }
  if (idx < IV) {
    float4 v = ((const float4*)it)[idx];
    half4_t h = {(_Float16)v.x, (_Float16)v.y, (_Float16)v.z, (_Float16)v.w};
    Ih[idx] = h;
  }
}

// ---------------- kernel 2: fused fp16 GEMM + per-query top-2 ---------------
// grid (TQ/BM, NSPLIT), block 256 = 4 waves stacked in q; wave tile 32q x 128i
// (2x8 grid of 16x16x32 MFMAs, 64 AGPR acc). Double-buffered staging,
// 1 barrier per kk. 3 blocks/CU target.
__global__ __launch_bounds__(256, 3) void score_kernel(char* __restrict__ ws) {
  __shared__ __align__(16) char sA[2][BM * 64];  // 2 x 8 KB
  __shared__ __align__(16) char sB[2][BN * 64];  // 2 x 8 KB  (total 32 KB)

  const int tid  = threadIdx.x;
  const int lane = tid & 63;
  const int wave = tid >> 6;
  const int quad = lane >> 4;
  const int l15  = lane & 15;
  const int qtile = blockIdx.x;
  const int split = blockIdx.y;

  const char* Qh = ws + QH_OFF;
  const char* Ih = ws + IH_OFF;

  // staging: lane-offset pattern f covers 64 rows x 64 B; 2 streams per tile
  const int f = (tid >> 2) * 1024 + (tid & 3) * 16;
  const char* gA0 = Qh + (size_t)qtile * BM * 1024 + f;  // q rows 0..63
  const char* gA1 = gA0 + 64 * 1024;                     // q rows 64..127
  const char* gB0 = Ih + (size_t)split * BN * 1024 + f;  // item rows 0..63
  const char* gB1 = gB0 + 64 * 1024;                     // item rows 64..127
  const int flat = tid * 16;  // LDS dest (wave-uniform base + lane*16)

  // fragment LDS byte offsets
  const int aBase = (wave * 32 + l15) * 64 + quad * 16;  // + mi*1024
  const int bBase = l15 * 64 + quad * 16;                // + ni*1024

  float4t acc[2][8];
#pragma unroll
  for (int mi = 0; mi < 2; ++mi)
#pragma unroll
    for (int ni = 0; ni < 8; ++ni) acc[mi][ni] = (float4t){0.f, 0.f, 0.f, 0.f};

  // preload kk=0 into buffer 0
  lds_load16(gA0, sA[0] + flat);
  lds_load16(gA1, sA[0] + flat + 4096);
  lds_load16(gB0, sB[0] + flat);
  lds_load16(gB1, sB[0] + flat + 4096);

#pragma unroll
  for (int kk = 0; kk < KITER; ++kk) {
    const int cur = kk & 1;
    const int nxt = cur ^ 1;
    // barrier: staging of kk drained (compiler vmcnt(0)); buf[nxt] free.
    __syncthreads();

    // prefetch kk+1 into the other buffer; delivery overlaps kk's compute.
    if (kk + 1 < KITER) {
      const int kb = (kk + 1) * 64;
      lds_load16(gA0 + kb, sA[nxt] + flat);
      lds_load16(gA1 + kb, sA[nxt] + flat + 4096);
      lds_load16(gB0 + kb, sB[nxt] + flat);
      lds_load16(gB1 + kb, sB[nxt] + flat + 4096);
    }

    half8 a[2], b[8];
#pragma unroll
    for (int mi = 0; mi < 2; ++mi)
      a[mi] = *(const half8*)(sA[cur] + aBase + mi * 1024);
#pragma unroll
    for (int ni = 0; ni < 8; ++ni)
      b[ni] = *(const half8*)(sB[cur] + bBase + ni * 1024);
#pragma unroll
    for (int mi = 0; mi < 2; ++mi)
#pragma unroll
      for (int ni = 0; ni < 8; ++ni)
        acc[mi][ni] = __builtin_amdgcn_mfma_f32_16x16x32_f16(
            a[mi], b[ni], acc[mi][ni], 0, 0, 0);
  }

  // ---- epilogue: top-2 over this wave's 128 cols, per query row ----
  // C row = quad*4+r (query), col = l15 (item). loc = ni*16+l15 < 128.
  float t1v[8], t2v[8];
  int pk[8];
#pragma unroll
  for (int s = 0; s < 8; ++s) { t1v[s] = -1e30f; t2v[s] = -1e30f; pk[s] = 0; }

#pragma unroll
  for (int ni = 0; ni < 8; ++ni) {
    const int loc = ni * 16 + l15;
#pragma unroll
    for (int mi = 0; mi < 2; ++mi) {
#pragma unroll
      for (int r = 0; r < 4; ++r) {
        const int s = mi * 4 + r;
        const float v = acc[mi][ni][r];
        const bool g1 = v > t1v[s];
        const bool g2 = v > t2v[s];
        const float nt2 = g1 ? t1v[s] : (g2 ? v : t2v[s]);
        const int pkA = (loc << 16) | ((unsigned)pk[s] >> 16);  // demote t1
        const int pkB = (pk[s] & (int)0xFFFF0000) | loc;        // replace t2
        pk[s] = g1 ? pkA : (g2 ? pkB : pk[s]);
        t1v[s] = g1 ? v : t1v[s];
        t2v[s] = nt2;
      }
    }
  }

  // 4-step butterfly merge across the 16-lane l15 group
  // (no tie-break: fp32-accumulated scores of random vectors never tie)
#pragma unroll
  for (int s = 0; s < 8; ++s) {
#pragma unroll
    for (int m = 1; m < 16; m <<= 1) {
      const float b1v = __shfl_xor(t1v[s], m, 16);
      const float b2v = __shfl_xor(t2v[s], m, 16);
      const int bpk  = __shfl_xor(pk[s], m, 16);
      const bool g = b1v > t1v[s];
      const float loserv = g ? t1v[s] : b1v;
      const int wpk = g ? bpk : pk[s];
      const int lpk = g ? pk[s] : bpk;
      const float ws2v = g ? b2v : t2v[s];   // winner-side second
      t1v[s] = g ? b1v : t1v[s];
      const bool g2 = loserv > ws2v;
      t2v[s] = g2 ? loserv : ws2v;
      const int pkOpt = (wpk & (int)0xFFFF0000) | ((unsigned)lpk >> 16);
      pk[s] = g2 ? pkOpt : wpk;
    }
  }

  // writer: l15 == 0. One entry per (qrow, split): waves cover disjoint qrows.
  if (l15 == 0) {
    float4* part = (float4*)(ws + PART_OFF);
#pragma unroll
    for (int s = 0; s < 8; ++s) {
      const int qrow = qtile * BM + wave * 32 + (s >> 2) * 16 + quad * 4 + (s & 3);
      const int i1 = split * BN + ((unsigned)pk[s] >> 16);
      const int i2 = split * BN + (pk[s] & 0xFFFF);
      float4 ent;
      ent.x = t1v[s];
      ent.y = __int_as_float(i1);
      ent.z = t2v[s];
      ent.w = __int_as_float(i2);
      part[(size_t)qrow * 32 + split] = ent;
    }
  }
}

// ---------------- kernel 3: merge partials + exact fp32 rescue --------------
// one wave per query; 32 partial entries -> global fp16 top-2 -> exact fp32
// re-score of both candidates from the ORIGINAL fp32 inputs.
__global__ __launch_bounds__(256) void rescue_kernel(
    const float* __restrict__ q, const float* __restrict__ items,
    const char* __restrict__ ws, float* __restrict__ out) {
  const int wave = threadIdx.x >> 6;
  const int lane = threadIdx.x & 63;
  const int qrow = blockIdx.x * 4 + wave;

  const float4* part = (const float4*)(ws + PART_OFF);

  float t1vv = -1e30f, t2vv = -1e30f;
  int t1i = 0x7FFFFFFF, t2i = 0x7FFFFFFF;
  if (lane < 32) {
    float4 ent = part[(size_t)qrow * 32 + lane];  // one coalesced 512B burst
    t1vv = ent.x; t1i = __float_as_int(ent.y);
    t2vv = ent.z; t2i = __float_as_int(ent.w);
  }
#pragma unroll
  for (int m = 1; m < 32; m <<= 1) {
    const float b1v = __shfl_xor(t1vv, m, 32);
    const int   b1i = __shfl_xor(t1i, m, 32);
    const float b2v = __shfl_xor(t2vv, m, 32);
    const int   b2i = __shfl_xor(t2i, m, 32);
    top2_merge(t1vv, t1i, t2vv, t2i, b1v, b1i, b2v, b2i);
  }
  const int c1i = __shfl(t1i, 0, 64);
  const int c2i = __shfl(t2i, 0, 64);

  const float4* qp = (const float4*)(q + (size_t)qrow * CD);
  const float4* p1 = (const float4*)(items + (size_t)c1i * CD);
  const float4* p2 = (const float4*)(items + (size_t)c2i * CD);
  float4 qa = qp[lane * 2], qb = qp[lane * 2 + 1];
  float4 xa = p1[lane * 2], xb = p1[lane * 2 + 1];
  float4 ya = p2[lane * 2], yb = p2[lane * 2 + 1];

  float d1 = qa.x * xa.x + qa.y * xa.y + qa.z * xa.z + qa.w * xa.w +
             qb.x * xb.x + qb.y * xb.y + qb.z * xb.z + qb.w * xb.w;
  float d2 = qa.x * ya.x + qa.y * ya.y + qa.z * ya.z + qa.w * ya.w +
             qb.x * yb.x + qb.y * yb.y + qb.z * yb.z + qb.w * yb.w;
  float qq = qa.x * qa.x + qa.y * qa.y + qa.z * qa.z + qa.w * qa.w +
             qb.x * qb.x + qb.y * qb.y + qb.z * qb.z + qb.w * qb.w;
  float i1 = xa.x * xa.x + xa.y * xa.y + xa.z * xa.z + xa.w * xa.w +
             xb.x * xb.x + xb.y * xb.y + xb.z * xb.z + xb.w * xb.w;
  float i2 = ya.x * ya.x + ya.y * ya.y + ya.z * ya.z + ya.w * ya.w +
             yb.x * yb.x + yb.y * yb.y + yb.z * yb.z + yb.w * yb.w;

#pragma unroll
  for (int m = 1; m < 64; m <<= 1) {
    d1 += __shfl_xor(d1, m, 64);
    d2 += __shfl_xor(d2, m, 64);
    qq += __shfl_xor(qq, m, 64);
    i1 += __shfl_xor(i1, m, 64);
    i2 += __shfl_xor(i2, m, 64);
  }

  if (lane == 0) {
    bool use2 = (d2 > d1) || (d2 == d1 && c2i < c1i);
    float d  = use2 ? d2 : d1;
    float nn = use2 ? i2 : i1;
    float nq = fmaxf(sqrtf(qq), 1e-12f);
    float np = fmaxf(sqrtf(nn), 1e-12f);
    out[qrow] = -(d / (nq * np));
  }
}

// ---------------------------------------------------------------------------
extern "C" void kernel_launch(void* const* d_in, const int* in_sizes, int n_in,
                              void* d_out, int out_size, void* d_ws,
                              size_t ws_size, hipStream_t stream) {
  const float* q  = (const float*)d_in[0];
  const float* it = (const float*)d_in[1];
  char* ws = (char*)d_ws;
  float* out = (float*)d_out;

  convert_kernel<<<TQ * CD / 4 / 256, 256, 0, stream>>>(q, it, ws);
  dim3 grid(TQ / BM, NSPLIT);
  score_kernel<<<grid, 256, 0, stream>>>(ws);
  rescue_kernel<<<TQ / 4, 256, 0, stream>>>(q, it, ws, out);
}